// Round 8
// baseline (158.078 us; speedup 1.0000x reference)
//
#include <hip/hip_runtime.h>
#include <math.h>

#define NQ 12
#define NL 4
#define NA 6
#define BATCH 4096
#define NT 256
#define RSTR 17   // float (b32) row stride for T_a view; odd -> conflict-free b32 floor

typedef float f2 __attribute__((ext_vector_type(2)));

// HW-verified (R3-R10) packed complex primitives; (re,im) in a VGPR pair.
#define CMUL(d, u, a)  asm("v_pk_mul_f32 %0, %1, %2 op_sel_hi:[0,1]"                 : "=v"(d) : "v"(u), "v"(a))
#define CMACR(d, u, a) asm("v_pk_fma_f32 %0, %1, %2, %0 op_sel_hi:[0,1,1]"           : "+v"(d) : "v"(u), "v"(a))
#define CMACI(d, u, a) asm("v_pk_fma_f32 %0, %1, %2, %0 op_sel:[1,1,0] op_sel_hi:[1,0,1] neg_lo:[1,0,0]" : "+v"(d) : "v"(u), "v"(a))
// R10-verified scalar-broadcast variants (coefficient f2 = (c,s)):
#define RYMULS(d, u, a)  asm("v_pk_mul_f32 %0, %1, %2 op_sel:[1,0] op_sel_hi:[1,1]"  : "=v"(d) : "v"(u), "v"(a))
#define RYMACNS(d, u, a) asm("v_pk_fma_f32 %0, %1, %2, %0 op_sel:[1,0,0] op_sel_hi:[1,1,1] neg_lo:[1,0,0] neg_hi:[1,0,0]" : "+v"(d) : "v"(u), "v"(a))
#define WFENCE() asm volatile("s_waitcnt lgkmcnt(0)" ::: "memory")

// Real RY butterfly: n0 = c*a0 - s*a1 ; n1 = s*a0 + c*a1   (4 pk ops)
#define RYBFLY(A0, A1, CS) do { \
    f2 _a0 = (A0), _a1 = (A1), _n0, _n1; \
    CMUL  (_n0, CS, _a0); RYMACNS(_n0, CS, _a1); \
    RYMULS(_n1, CS, _a0); CMACR  (_n1, CS, _a1); \
    (A0) = _n0; (A1) = _n1; } while (0)

#define RYGATE(gidx, bq) do { \
    const f2 cs = *(const f2*)(rots + (gidx) * 2); \
    const int S = 1 << (bq); \
    _Pragma("unroll") \
    for (int m = 0; m < 8; ++m) { \
        const int j0 = ((m & ~(S - 1)) << 1) | (m & (S - 1)); \
        RYBFLY(st[j0], st[j0 + S], cs); \
    } } while (0)

// Circuit algebra (R10-verified): Rot = RZ(omega)*RY(theta)*RZ(phi); diagonals folded:
// RZ(phi_0) into init; D_l = RZ(omega_l)*CZ*RZ(phi_{l+1}) between RY layers; trailing
// RZ(omega_3)+CZ_3 dropped (probs phase-invariant).
// Layouts (R8-verified): L1: i=(lam5..lam0,w1,w0,j3..j0); L2: i=(lam5,lam4,j3..j0,w1,w0,lam3..0);
// L3: i=(j3,j2,lam5,lam4,w1,w0,j1,j0,lam3..0).
// T_a (L1<->L2, involution, wave-local, b32 re/im passes over float[256][17]) — R12-verified.
// R18 T_b (L2<->L3, involution, cross-wave): b64 TEMP-FREE two-phase over f2[256][9] (18432 B).
//   Pairing: (t=(w,l54,l15), j) <-> (t'=((j&3)<<6)|((j>>2)<<4)|l15, j'=(l54<<2)|w).
//   (w + (j&3)) parity is INVARIANT -> closed halves: phase A = slots with (j&1)==w0,
//   phase B = rest (8 slots each, wave-uniform predicate). Each phase stages its own originals
//   then reads its own partners -> reads never clobber values a later write needs -> ZERO temps
//   (R14's fatal +16 VGPR avoided). Write: buf9[tix*9 + (j>>1)]; read:
//   buf9[(l15*9 + l54*2 + w1) + cj*9], cj=((j&3)<<6)|((j>>2)<<4) -> base + imm only (R11 lesson).
//   Banks: writes 18t+2k and reads 18*l15+4*l54+2*w1 mod 32 both span 16 even residues x4
//   lanes = b64 floor. 32 b64 ops vs 64 b32.
//   R17 FAILURE ROOT CAUSE (fixed here): the 9-stride f2 rows are NOT wave-block-aligned with
//   the 17-stride T_a view (1152 vs 1088 floats/wave-block), so wave w's TB writes spill into
//   wave w+1's T_a float region -> entering T_b through a per-wave WFENCE raced other waves'
//   in-flight T_a reads. Fix: TB_FULL begins with __syncthreads() (4 barriers total inside).
// R15 (verified 94.6us kernel): (a) Walsh epilogue; (b) beta-table in d_ws.
// R16: setup_kernel at 256 threads (A/B vs R15: no graded change -> setup not on critical path).
// d_ws float layout: [0..95] 48 gates (c,s) | [96..143] alphas[4][12] | [144..271] dreg[4][16]
//   (re,im) | [272..2319] beta table: (cos,sin) of beta_r(tix) for r=0..3, tix=0..255.

__global__ void setup_kernel(const float* __restrict__ weights, float* __restrict__ ws) {
    __shared__ float alph_s[NL * NQ];
    const int t = threadIdx.x;   // 256 threads
    if (t < NL * NQ) {
        const float th = weights[t * 3 + 1];
        float s, c;
        sincosf(0.5f * th, &s, &c);
        ws[t * 2 + 0] = c; ws[t * 2 + 1] = s;
        const int r = t / NQ, q = t % NQ;
        float a;
        if (r == 0) a = 0.5f * weights[q * 3 + 0];
        else        a = 0.5f * (weights[((r - 1) * NQ + q) * 3 + 2] +
                                 weights[(r * NQ + q) * 3 + 0]);
        ws[96 + t] = a;
        alph_s[t] = a;
    }
    if (t < 64) {
        const int d = t >> 4, j = t & 15;
        int wq[4];
        if (d == 1 || d == 3) { wq[0] = 0; wq[1] = 1; wq[2] = 6; wq[3] = 7; }
        else                  { wq[0] = 8; wq[1] = 9; wq[2] = 10; wq[3] = 11; }
        float g = 0.0f;
#pragma unroll
        for (int k = 0; k < 4; ++k) {
            const int q = wq[k];
            const float a = (d == 0) ? 0.5f * weights[q * 3 + 0]
                                     : 0.5f * (weights[((d - 1) * NQ + q) * 3 + 2] +
                                               weights[(d * NQ + q) * 3 + 0]);
            g += ((j >> (3 - k)) & 1) ? a : -a;
        }
        float sg, cg;
        sincosf(g, &sg, &cg);
        ws[144 + (d * 16 + j) * 2 + 0] = cg;
        ws[144 + (d * 16 + j) * 2 + 1] = sg;
    }
    __syncthreads();
    // beta table: 4 rows x 256 thread-positions, one row per thread; even r -> L1, odd r -> L3.
    {
        const int lam = t & 63, wv = t >> 6;
        const int w1 = (wv >> 1) & 1, w0 = wv & 1;
#pragma unroll
        for (int r = 0; r < 4; ++r) {
            const float* al = alph_s + r * NQ;
            float beta;
            if ((r & 1) == 0) {   // BETA_L1
                beta = (((lam >> 5) & 1) ? al[0] : -al[0]) + (((lam >> 4) & 1) ? al[1] : -al[1])
                     + (((lam >> 3) & 1) ? al[2] : -al[2]) + (((lam >> 2) & 1) ? al[3] : -al[3])
                     + (((lam >> 1) & 1) ? al[4] : -al[4]) + (((lam >> 0) & 1) ? al[5] : -al[5])
                     + (w1 ? al[6] : -al[6]) + (w0 ? al[7] : -al[7]);
            } else {              // BETA_L3
                beta = (((lam >> 5) & 1) ? al[2] : -al[2]) + (((lam >> 4) & 1) ? al[3] : -al[3])
                     + (w1 ? al[4] : -al[4]) + (w0 ? al[5] : -al[5])
                     + (((lam >> 3) & 1) ? al[8] : -al[8]) + (((lam >> 2) & 1) ? al[9] : -al[9])
                     + (((lam >> 1) & 1) ? al[10] : -al[10]) + (((lam >> 0) & 1) ? al[11] : -al[11]);
            }
            float sb, cb;
            sincosf(beta, &sb, &cb);
            ws[272 + (r * 256 + t) * 2 + 0] = cb;
            ws[272 + (r * 256 + t) * 2 + 1] = sb;
        }
    }
}

// st[j] *= Dth * dreg_tab[j]   (R10-verified core; R15: Dth from beta table)
__device__ __forceinline__ void apply_phase(f2* st, const float* tab, f2 Dth) {
#pragma unroll
    for (int j = 0; j < 16; ++j) {
        const f2 a = st[j];
        f2 t, u;
        CMUL(t, Dth, a); CMACI(t, Dth, a);
        const f2 dg = *(const f2*)(tab + 2 * j);
        CMUL(u, dg, t); CMACI(u, dg, t);
        st[j] = u;
    }
}

__global__ __launch_bounds__(NT) void qdqn_kernel(
    const float* __restrict__ x,       // [BATCH,12]
    const float* __restrict__ rots,    // d_ws tables
    const float* __restrict__ fc_w,    // [6,12]
    const float* __restrict__ fc_b,    // [6]
    float* __restrict__ out)           // [BATCH,6]
{
    // 18432 B dual-view buffer: f2[256][9] (T_b, b64) ; float[256][17] view (T_a, b32, 17408 B)
    __shared__ __align__(16) f2 buf9[256 * 9];
    float* const bufr = (float*)buf9;
    __shared__ float encc[NQ], encs[NQ];
    __shared__ float red[4][NQ];
    __shared__ float qout[NQ];

    const int tix = threadIdx.x;
    const int lam = tix & 63;
    const int w   = tix >> 6;
    const int w1  = (w >> 1) & 1, w0 = w & 1;
    const int b   = blockIdx.x;

    const float* dreg = rots + 144;
    const float* btab = rots + 272;

    if (tix < NQ) {
        float s, c;
        sincosf(0.5f * x[b * NQ + tix], &s, &c);
        encc[tix] = c; encs[tix] = s;
    }
    __syncthreads();

    // --- RY product state in L1 (real) ---
    f2 st[16];
    {
        float pre = 1.0f;
#pragma unroll
        for (int q = 0; q < 6; ++q)
            pre *= ((lam >> (5 - q)) & 1) ? encs[q] : encc[q];
        pre *= w1 ? encs[6] : encc[6];
        pre *= w0 ? encs[7] : encc[7];
        const float c8 = encc[8],  s8 = encs[8];
        const float c9 = encc[9],  s9 = encs[9];
        const float cA = encc[10], sA = encs[10];
        const float cB = encc[11], sB = encs[11];
#pragma unroll
        for (int j = 0; j < 16; ++j) {
            float v = pre;
            v *= (j & 8) ? s8 : c8;
            v *= (j & 4) ? s9 : c9;
            v *= (j & 2) ? sA : cA;
            v *= (j & 1) ? sB : cB;
            st[j] = (f2){ v, 0.0f };
        }
    }

    // --- init diagonal: RZ(phi_0) in L1 (beta row 0) ---
    apply_phase(st, dreg + 0 * 32, *(const f2*)(btab + (0 * 256 + tix) * 2));

    const int row_a = (w << 6) | (lam & 0x30);
    const int col_a = lam & 0xF;
    // T_b read base: l15*9 + l54*2 + w1  (col = partner's write rank; R17 derivation)
    const int tb_rbase = (lam & 15) * 9 + ((lam >> 4) & 3) * 2 + w1;

    // T_a (wave-local throughout: wave w only touches float-rows (w<<6)..(w<<6)+63): fences only.
#define TRANSPOSE_A_FWD() do { \
    WFENCE(); \
    _Pragma("unroll") for (int j = 0; j < 16; ++j) bufr[tix * RSTR + j] = st[j].x; \
    WFENCE(); \
    _Pragma("unroll") for (int j = 0; j < 16; ++j) st[j].x = bufr[(row_a + j) * RSTR + col_a]; \
    WFENCE(); \
    _Pragma("unroll") for (int j = 0; j < 16; ++j) bufr[tix * RSTR + j] = st[j].y; \
    WFENCE(); \
    _Pragma("unroll") for (int j = 0; j < 16; ++j) st[j].y = bufr[(row_a + j) * RSTR + col_a]; \
    } while (0)

    // T_b b64 temp-free two-phase (R18; see header). PAR = (j&1) of this wave's phase-A slots.
#define TB_W(PAR) do { _Pragma("unroll") \
    for (int j = (PAR); j < 16; j += 2) buf9[tix * 9 + (j >> 1)] = st[j]; } while (0)
#define TB_R(PAR) do { _Pragma("unroll") \
    for (int j = (PAR); j < 16; j += 2) \
        st[j] = buf9[tb_rbase + ((((j & 3) << 6) | ((j >> 2) << 4)) * 9)]; } while (0)

    // Leading barrier is mandatory (R17 root cause): 9-stride TB writes are NOT wave-local
    // relative to the 17-stride T_a rows other waves may still be reading.
#define TB_FULL() do { \
    __syncthreads(); \
    if (w0 == 0) TB_W(0); else TB_W(1); \
    __syncthreads(); \
    if (w0 == 0) TB_R(0); else TB_R(1); \
    __syncthreads(); \
    if (w0 == 0) TB_W(1); else TB_W(0); \
    __syncthreads(); \
    if (w0 == 0) TB_R(1); else TB_R(0); \
    } while (0)

#pragma unroll 1
    for (int h = 0; h < 2; ++h) {
        // ============ forward layer l = 2h : L1 -> L2 -> L3 ============
        {
            const int gb = (2 * h) * NQ;
            RYGATE(gb + 11, 0); RYGATE(gb + 10, 1); RYGATE(gb + 9, 2); RYGATE(gb + 8, 3);
            TRANSPOSE_A_FWD();                      // wave-local (prior readers in-wave or none)
            RYGATE(gb + 5, 0); RYGATE(gb + 4, 1); RYGATE(gb + 3, 2); RYGATE(gb + 2, 3);
            TB_FULL();                              // L2 -> L3 (leading barrier inside)
            RYGATE(gb + 7, 0); RYGATE(gb + 6, 1); RYGATE(gb + 1, 2); RYGATE(gb + 0, 3);
            // CZ sign in L3 (R8-verified)
            {
                const int l5 = (lam >> 5) & 1, l4 = (lam >> 4) & 1, l3 = (lam >> 3) & 1;
                const int par = (l5 & l4) + (l4 & w1) + (w1 & w0) + __popc(lam & (lam >> 1) & 0x7);
                const float base = (par & 1) ? -1.0f : 1.0f;
                const float fA = l5 ? -1.0f : 1.0f;
                const float fB = w0 ? -1.0f : 1.0f;
                const float fC = l3 ? -1.0f : 1.0f;
#pragma unroll
                for (int j = 0; j < 16; ++j) {
                    float s = base;
                    if (j & 4) s *= fA;
                    if (j & 2) s *= fB;
                    if (j & 1) s *= fC;
                    if ((((j & 12) == 12) ? 1 : 0) ^ (((j & 3) == 3) ? 1 : 0)) s = -s;
                    st[j] *= s;
                }
            }
            // fused RZ diagonal, row 2h+1, in L3 (beta row 2h+1, L3 form)
            apply_phase(st, dreg + (2 * h + 1) * 32,
                        *(const f2*)(btab + ((2 * h + 1) * 256 + tix) * 2));
        }
        // ============ reverse layer l = 2h+1 : L3 -> L2 -> L1 ============
        {
            const int gb = (2 * h + 1) * NQ;
            RYGATE(gb + 7, 0); RYGATE(gb + 6, 1); RYGATE(gb + 1, 2); RYGATE(gb + 0, 3);
            TB_FULL();                              // L3 -> L2 (involution; leading barrier inside)
            RYGATE(gb + 5, 0); RYGATE(gb + 4, 1); RYGATE(gb + 3, 2); RYGATE(gb + 2, 3);
            // T_a back (prior T_b reads cross-wave -> barrier before writes; then wave-local)
            __syncthreads();
#pragma unroll
            for (int j = 0; j < 16; ++j) bufr[tix * RSTR + j] = st[j].x;
            WFENCE();
#pragma unroll
            for (int j = 0; j < 16; ++j) st[j].x = bufr[(row_a + j) * RSTR + col_a];
            WFENCE();
#pragma unroll
            for (int j = 0; j < 16; ++j) bufr[tix * RSTR + j] = st[j].y;
            WFENCE();
#pragma unroll
            for (int j = 0; j < 16; ++j) st[j].y = bufr[(row_a + j) * RSTR + col_a];
            RYGATE(gb + 11, 0); RYGATE(gb + 10, 1); RYGATE(gb + 9, 2); RYGATE(gb + 8, 3);
            if (h == 0) {
                // CZ sign in L1 (R6/R8-verified)
                {
                    const int par = __popc(lam & (lam >> 1)) + ((lam & 1) & w1) + (w1 & w0);
                    const float base = (par & 1) ? -1.0f : 1.0f;
                    const float sHi = w0 ? -base : base;
#pragma unroll
                    for (int j = 0; j < 16; ++j) {
                        float s = (j & 8) ? sHi : base;
                        if (__popc(j & (j >> 1)) & 1) s = -s;
                        st[j] *= s;
                    }
                }
                // fused RZ diagonal, row 2, in L1 (beta row 2, L1 form)
                apply_phase(st, dreg + 2 * 32, *(const f2*)(btab + (2 * 256 + tix) * 2));
            }
            // h==1: trailing diagonals dropped (probs phase-invariant)
        }
    }

    // --- measurement in L1 ---
    float tot = 0.f, m8 = 0.f, m9 = 0.f, m10 = 0.f, m11 = 0.f;
#pragma unroll
    for (int j = 0; j < 16; ++j) {
        const float p = st[j].x * st[j].x + st[j].y * st[j].y;
        tot += p;
        m8  += (j & 8) ? -p : p;
        m9  += (j & 4) ? -p : p;
        m10 += (j & 2) ? -p : p;
        m11 += (j & 1) ? -p : p;
    }

    // Walsh reduction (R14-HW-verified signs): part[q] = (lam bit (5-q)) ? -tot : +tot
    // -> spawn D = S - p (low half minus high half) at the stage crossing that bit.
    float S = tot, D5, D4, D3, D2, D1, D0, p;
    p = __shfl_down(S, 32, 64); D5 = S - p; S += p;
    p = __shfl_down(S, 16, 64); D4 = S - p; S += p;
    D5 += __shfl_down(D5, 16, 64);
    p = __shfl_down(S, 8, 64);  D3 = S - p; S += p;
    D5 += __shfl_down(D5, 8, 64); D4 += __shfl_down(D4, 8, 64);
    p = __shfl_down(S, 4, 64);  D2 = S - p; S += p;
    D5 += __shfl_down(D5, 4, 64); D4 += __shfl_down(D4, 4, 64); D3 += __shfl_down(D3, 4, 64);
    p = __shfl_down(S, 2, 64);  D1 = S - p; S += p;
    D5 += __shfl_down(D5, 2, 64); D4 += __shfl_down(D4, 2, 64); D3 += __shfl_down(D3, 2, 64);
    D2 += __shfl_down(D2, 2, 64);
    p = __shfl_down(S, 1, 64);  D0 = S - p; S += p;
    D5 += __shfl_down(D5, 1, 64); D4 += __shfl_down(D4, 1, 64); D3 += __shfl_down(D3, 1, 64);
    D2 += __shfl_down(D2, 1, 64); D1 += __shfl_down(D1, 1, 64);
#pragma unroll
    for (int off = 32; off > 0; off >>= 1) {
        m8  += __shfl_down(m8,  off, 64);
        m9  += __shfl_down(m9,  off, 64);
        m10 += __shfl_down(m10, off, 64);
        m11 += __shfl_down(m11, off, 64);
    }

    if (lam == 0) {
        red[w][0] = D5; red[w][1] = D4; red[w][2] = D3;
        red[w][3] = D2; red[w][4] = D1; red[w][5] = D0;
        red[w][6] = S;
        red[w][7] = m8; red[w][8] = m9; red[w][9] = m10; red[w][10] = m11;
    }
    __syncthreads();
    if (tix < NQ) {
        float v;
        if (tix < 6)       v = red[0][tix] + red[1][tix] + red[2][tix] + red[3][tix];
        else if (tix == 6) v = red[0][6] + red[1][6] - red[2][6] - red[3][6];  // w1 set for w>=2
        else if (tix == 7) v = red[0][6] - red[1][6] + red[2][6] - red[3][6];  // w0 set for odd w
        else { const int k = tix - 1; v = red[0][k] + red[1][k] + red[2][k] + red[3][k]; }
        qout[tix] = v;
    }
    __syncthreads();

    if (tix < NA) {
        float acc = fc_b[tix];
#pragma unroll
        for (int q = 0; q < NQ; ++q)
            acc += qout[q] * fc_w[tix * NQ + q];
        out[b * NA + tix] = acc;
    }
}

extern "C" void kernel_launch(void* const* d_in, const int* in_sizes, int n_in,
                              void* d_out, int out_size, void* d_ws, size_t ws_size,
                              hipStream_t stream) {
    const float* x   = (const float*)d_in[0];
    const float* wts = (const float*)d_in[1];
    const float* fcw = (const float*)d_in[2];
    const float* fcb = (const float*)d_in[3];
    float* tabs = (float*)d_ws;   // 2320 f32 = 9280 B (gates/alphas/dreg + beta table)
    setup_kernel<<<1, 256, 0, stream>>>(wts, tabs);
    qdqn_kernel<<<BATCH, NT, 0, stream>>>(x, tabs, fcw, fcb, (float*)d_out);
}